// Round 18
// baseline (269.999 us; speedup 1.0000x reference)
//
#include <hip/hip_runtime.h>
#include <hip/hip_bf16.h>
#include <stdint.h>

#define TOKENS 4096
#define IN_F   4096
#define OUT_F  11008
#define PACKS  512          // IN_F/8
#define GCOUNT 32           // IN_F/128

#define BM 256
#define BN 256
#define BK 128
#define NKT (IN_F / BK)     // 32

typedef __attribute__((ext_vector_type(8))) short bf16x8;
typedef __attribute__((ext_vector_type(4))) float f32x4;
typedef __attribute__((ext_vector_type(4))) int i32x4;
typedef __attribute__((ext_vector_type(16))) int i32x16;

#define AS1 __attribute__((address_space(1)))
#define AS3 __attribute__((address_space(3)))

static __device__ __forceinline__ short f2bf(float f) {
    union { __hip_bfloat16 h; short s; } u;
    u.h = __float2bfloat16(f);
    return u.s;
}

// ---------------- pre-pass 1: x fp32 -> i8 per-row (sx[row] = amax/127) ----------------
__global__ __launch_bounds__(256) void quant_x_kernel(const float* __restrict__ x,
                                                      signed char* __restrict__ xq,
                                                      float* __restrict__ sx) {
    const int row = blockIdx.x;
    const int t = threadIdx.x;
    const float4* src = (const float4*)(x + (size_t)row * IN_F);
    float4 v[4];
    float am = 0.0f;
#pragma unroll
    for (int i = 0; i < 4; ++i) {
        v[i] = src[t + 256 * i];
        am = fmaxf(am, fmaxf(fmaxf(fabsf(v[i].x), fabsf(v[i].y)),
                             fmaxf(fabsf(v[i].z), fabsf(v[i].w))));
    }
#pragma unroll
    for (int off = 32; off >= 1; off >>= 1)
        am = fmaxf(am, __shfl_xor(am, off));
    __shared__ float wmax[4];
    if ((t & 63) == 0) wmax[t >> 6] = am;
    __syncthreads();
    float amax = fmaxf(fmaxf(wmax[0], wmax[1]), fmaxf(wmax[2], wmax[3]));
    amax = fmaxf(amax, 1e-20f);
    const float rs = 127.0f / amax;
    int* dst = (int*)(xq + (size_t)row * IN_F);
#pragma unroll
    for (int i = 0; i < 4; ++i) {
        float fv[4] = {v[i].x, v[i].y, v[i].z, v[i].w};
        int p = 0;
#pragma unroll
        for (int j = 0; j < 4; ++j) {
            int q = __float2int_rn(fv[j] * rs);
            q = max(-127, min(127, q));
            p |= (q & 255) << (8 * j);
        }
        dst[t + 256 * i] = p;
    }
    if (t == 0) sx[row] = amax * (1.0f / 127.0f);
}

// ---------------- pre-pass 2: per-column W scale Sw[o] = max_g s*max(z,15-z) / 127 ----------------
__global__ __launch_bounds__(256) void sw_kernel(const int* __restrict__ qz,
                                                 const float* __restrict__ sc,
                                                 float* __restrict__ sw,
                                                 float* __restrict__ rw) {
    int o = blockIdx.x * 256 + threadIdx.x;      // 43*256 == 11008 exactly
    float wmax = 0.f;
#pragma unroll 8
    for (int g = 0; g < GCOUNT; ++g) {
        float s = sc[(size_t)g * OUT_F + o];
        int z = qz[(size_t)g * OUT_F + o];
        float m = (float)max(z, 15 - z);
        wmax = fmaxf(wmax, s * m);
    }
    sw[o] = wmax * (1.0f / 127.0f);
    rw[o] = 127.0f / wmax;
}

// ---------------- pre-pass 3: W8[o,k] = round((q-z)*s[g,o]/Sw[o]) in [-127,127] ----------------
__global__ __launch_bounds__(256) void quant_w8_kernel(const int* __restrict__ qw,
                                                       const int* __restrict__ qz,
                                                       const float* __restrict__ sc,
                                                       const float* __restrict__ rw,
                                                       signed char* __restrict__ wq) {
    int i = blockIdx.x * 256 + threadIdx.x;   // pack index: o*512 + p
    int o = i >> 9, p = i & 511, g = p >> 4;
    int z = qz[(size_t)g * OUT_F + o];
    float f = sc[(size_t)g * OUT_F + o] * rw[o];
    int w = qw[i];
    int lo = 0, hi = 0;
#pragma unroll
    for (int j = 0; j < 4; ++j) {
        int d = __float2int_rn((float)(((w >> (4 * j)) & 15) - z) * f);
        d = max(-127, min(127, d));
        lo |= (d & 255) << (8 * j);
    }
#pragma unroll
    for (int j = 4; j < 8; ++j) {
        int d = __float2int_rn((float)(((w >> (4 * j)) & 15) - z) * f);
        d = max(-127, min(127, d));
        hi |= (d & 255) << (8 * (j - 4));
    }
    ((int2*)wq)[i] = make_int2(lo, hi);
}

// ---------------- staging: i8 tile 256 rows x 128, 16B chunks, XOR-swizzled source ----------------
// LDS position (r, c) holds logical chunk c ^ (r&7); reader applies the same XOR.
__device__ __forceinline__ void stage_i8(const signed char* __restrict__ G, int grow0,
                                         int kt, signed char* lds, int tid) {
#pragma unroll
    for (int i = 0; i < 4; ++i) {
        int CH = i * 512 + tid;                  // chunk 0..2047
        int r = CH >> 3;
        int c = (CH & 7) ^ (r & 7);              // inverse swizzle on SOURCE
        const signed char* g = G + (size_t)(grow0 + r) * IN_F + kt + c * 16;
        __builtin_amdgcn_global_load_lds((const AS1 void*)g,
                                         (AS3 void*)(lds + CH * 16), 16, 0, 0);
    }
}

// read all 6 fragments of kstep S (A: 4 m-tiles, B: 2 n-tiles)
#define READK(S)                                                                \
    _Pragma("unroll") for (int m = 0; m < 4; ++m)                               \
        a[S][m] = *(const i32x4*)(At + rA[m] + csk[S]);                         \
    _Pragma("unroll") for (int n = 0; n < 2; ++n)                               \
        b[S][n] = *(const i32x4*)(Bt + rB[n] + csk[S]);

// 8 MFMA of 32x32x32 for kstep S
#define OCTI(S)                                                                 \
    __builtin_amdgcn_s_setprio(1);                                              \
    _Pragma("unroll") for (int m = 0; m < 4; ++m)                               \
    _Pragma("unroll") for (int n = 0; n < 2; ++n)                               \
        acc[m][n] = __builtin_amdgcn_mfma_i32_32x32x32_i8(                      \
            a[S][m], b[S][n], acc[m][n], 0, 0, 0);                              \
    __builtin_amdgcn_s_setprio(0);

// ---------------- i8 GEMM: 256x256, BK=128, 32x32x32 MFMA, 2 barriers/K-tile ----------------
// Per wave (8 waves 2Mx4N): output 128x64 = 4x2 tiles of 32x32; acc[4][2] i32x16.
// K split into 4 ksteps of K=32; kstep s read in sub(s or 2), consumed per schedule:
//  sub0: READK(0); stage B(t+1); MFMA k2(t-1)
//  sub1: READK(1); MFMA k3(t-1)
//  sub2: READK(2)+READK(3); MFMA k0(t); lgkmcnt(0)+barrier  [fence a]
//  sub3: stage A(t+2); MFMA k1(t); vmcnt(4)+barrier          [fence b]
// Fragment layout (32x32x32 i8): A row=l&31, k=(l>>5)*16+e; B col=l&31 mirror;
// C/D col=l&31, row=(j&3)+8*(j>>2)+4*(l>>5) [guide-verified, shape-determined].
// vmcnt ledger @fence b: A(t+1)[4] + B(t+1)[4] + A(t+2)[4] -> vmcnt(4).
__global__ __launch_bounds__(512, 2) void gemm_i8_kernel(const signed char* __restrict__ A,
                                                         const signed char* __restrict__ B,
                                                         const float* __restrict__ sw,
                                                         const float* __restrict__ sx,
                                                         float* __restrict__ C) {
    __shared__ signed char As[2][BM * BK];   // 2 x 32 KB
    __shared__ signed char Bs[2][BN * BK];   // 2 x 32 KB (128 KB total)

    const int nbn = OUT_F / BN;              // 43
    const int nwg = (TOKENS / BM) * nbn;     // 688 = 8*86
    const int cpx = nwg >> 3;
    int bid = blockIdx.x;
    int swzb = (bid & 7) * cpx + (bid >> 3); // XCD-contiguous (bijective)
    int bm = swzb / nbn, bn = swzb % nbn;
    const int row0 = bm * BM, col0 = bn * BN;

    const int tid = threadIdx.x;
    const int lane = tid & 63;
    const int wid = tid >> 6;                // 8 waves: 2M x 4N
    const int wm = wid >> 2, wn = wid & 3;
    const int l31 = lane & 31, lh5 = lane >> 5, l7 = lane & 7;

    int csk[4];
#pragma unroll
    for (int s = 0; s < 4; ++s)
        csk[s] = ((2 * s + lh5) ^ l7) * 16;      // swizzled chunk byte offset, kstep s
    int rA[4], rB[2];
#pragma unroll
    for (int m = 0; m < 4; ++m) rA[m] = (wm * 128 + m * 32 + l31) * BK;
#pragma unroll
    for (int n = 0; n < 2; ++n) rB[n] = (wn * 64 + n * 32 + l31) * BK;

    i32x16 acc[4][2] = {};
    i32x4 a[4][4], b[4][2];

    // prologue: A(0)->As[0], B(0)->Bs[0], A(1)->As[1]; A0,B0 landed, A1 in flight
    stage_i8(A, row0, 0, &As[0][0], tid);
    stage_i8(B, col0, 0, &Bs[0][0], tid);
    stage_i8(A, row0, BK, &As[1][0], tid);
    asm volatile("s_waitcnt vmcnt(4)" ::: "memory");
    __builtin_amdgcn_s_barrier();

    for (int t = 0; t < NKT; ++t) {
        const int cab = t & 1;
        const signed char* At = &As[cab][0];
        const signed char* Bt = &Bs[cab][0];

        // ---- sub0: read k0; stage B(t+1)->Bs[cab^1]; MFMA k2(t-1) ----
        READK(0);
        if (t + 1 < NKT) stage_i8(B, col0, (t + 1) * BK, &Bs[cab ^ 1][0], tid);
        __builtin_amdgcn_sched_barrier(0);
        if (t > 0) { OCTI(2); }

        // ---- sub1: read k1; MFMA k3(t-1) ----
        READK(1);
        __builtin_amdgcn_sched_barrier(0);
        if (t > 0) { OCTI(3); }

        // ---- sub2: read k2,k3; MFMA k0(t); fence (a) ----
        READK(2);
        READK(3);
        __builtin_amdgcn_sched_barrier(0);
        OCTI(0);
        asm volatile("s_waitcnt lgkmcnt(0)" ::: "memory");
        __builtin_amdgcn_sched_barrier(0);
        __builtin_amdgcn_s_barrier();

        // ---- sub3: stage A(t+2)->As[cab]; MFMA k1(t); fence (b) ----
        if (t + 2 < NKT) stage_i8(A, row0, (t + 2) * BK, &As[cab][0], tid);
        __builtin_amdgcn_sched_barrier(0);
        OCTI(1);
        if (t < NKT - 2) {
            asm volatile("s_waitcnt vmcnt(4)" ::: "memory");   // t+1 landed; A(t+2) in flight
        } else if (t == NKT - 2) {
            asm volatile("s_waitcnt vmcnt(0)" ::: "memory");
        }
        __builtin_amdgcn_s_barrier();
    }

    // ---- pipeline tail: k2(31), k3(31) ----
    { OCTI(2); }
    { OCTI(3); }

    // ---- epilogue: C = sx[row] * Sw[col] * acc ----
#pragma unroll
    for (int m = 0; m < 4; ++m) {
        const int rb = row0 + wm * 128 + m * 32 + 4 * lh5;
        f32x4 sxv[4];
#pragma unroll
        for (int g = 0; g < 4; ++g)
            sxv[g] = *(const f32x4*)(sx + rb + 8 * g);
#pragma unroll
        for (int n = 0; n < 2; ++n) {
            const int c = col0 + wn * 64 + n * 32 + l31;
            const float swc = sw[c];
#pragma unroll
            for (int j = 0; j < 16; ++j) {
                const int g = j >> 2, jj = j & 3;
                const int r = rb + 8 * g + jj;
                C[(size_t)r * OUT_F + c] = sxv[g][jj] * swc * (float)acc[m][n][j];
            }
        }
    }
}

// ---------------- fallback: fused dequant GEMM (128-tile bf16, known-good) ----------------
__device__ __forceinline__ void mfma_tile128(const short* As, const short* Bs,
                                             f32x4 acc[4][4], int lane, int wm, int wn) {
#pragma unroll
    for (int kk = 0; kk < 64; kk += 32) {
        const int kb = kk + (lane >> 4) * 8;
        bf16x8 af[4], bfr[4];
#pragma unroll
        for (int m = 0; m < 4; ++m) {
            int r = wm * 64 + m * 16 + (lane & 15);
            af[m] = *(const bf16x8*)(As + r * 64 + kb);
        }
#pragma unroll
        for (int n = 0; n < 4; ++n) {
            int c = wn * 64 + n * 16 + (lane & 15);
            bfr[n] = *(const bf16x8*)(Bs + c * 64 + kb);
        }
#pragma unroll
        for (int m = 0; m < 4; ++m)
#pragma unroll
            for (int n = 0; n < 4; ++n)
                acc[m][n] = __builtin_amdgcn_mfma_f32_16x16x32_bf16(af[m], bfr[n],
                                                                    acc[m][n], 0, 0, 0);
    }
}

__global__ __launch_bounds__(256) void gemm_fused_kernel(const float* __restrict__ x,
                                                         const int* __restrict__ qw,
                                                         const int* __restrict__ qz,
                                                         const float* __restrict__ sc,
                                                         float* __restrict__ C) {
    const int nbn = OUT_F / 128;
    const int nwg = (TOKENS / 128) * nbn;
    const int cpx = nwg >> 3;
    int bid = blockIdx.x;
    int swzb = (bid & 7) * cpx + (bid >> 3);
    int bm = swzb / nbn, bn = swzb % nbn;
    const int row0 = bm * 128, col0 = bn * 128;

    __shared__ short As[128 * 64];
    __shared__ short Bs[128 * 64];

    const int tid = threadIdx.x;
    const int lane = tid & 63;
    const int wid = tid >> 6;
    const int wm = wid >> 1, wn = wid & 1;

    f32x4 acc[4][4] = {};

    for (int kt = 0; kt < IN_F; kt += 64) {
#pragma unroll
        for (int i = 0; i < 4; ++i) {
            int idx = i * 256 + tid;
            int r = idx >> 3, kc = (idx & 7) * 8;
            const float4* src = (const float4*)(x + (size_t)(row0 + r) * IN_F + kt + kc);
            float4 aa = src[0], bb = src[1];
            bf16x8 v;
            v[0] = f2bf(aa.x); v[1] = f2bf(aa.y); v[2] = f2bf(aa.z); v[3] = f2bf(aa.w);
            v[4] = f2bf(bb.x); v[5] = f2bf(bb.y); v[6] = f2bf(bb.z); v[7] = f2bf(bb.w);
            *(bf16x8*)(As + r * 64 + kc) = v;
        }
        {
            int ol = tid >> 1;
            int kc = (tid & 1) * 32;
            const int4* src = (const int4*)(qw + (size_t)(col0 + ol) * PACKS + ((kt + kc) >> 3));
            int4 w4 = *src;
            int g = kt >> 7;
            float z = (float)qz[(size_t)g * OUT_F + col0 + ol];
            float s = sc[(size_t)g * OUT_F + col0 + ol];
            float zs = z * s;
            const int* wp = (const int*)&w4;
#pragma unroll
            for (int c2 = 0; c2 < 4; ++c2) {
                int w32 = wp[c2];
                bf16x8 v;
#pragma unroll
                for (int j = 0; j < 8; ++j)
                    v[j] = f2bf((float)((w32 >> (4 * j)) & 15) * s - zs);
                *(bf16x8*)(Bs + ol * 64 + kc + c2 * 8) = v;
            }
        }
        __syncthreads();
        mfma_tile128(As, Bs, acc, lane, wm, wn);
        __syncthreads();
    }
#pragma unroll
    for (int m = 0; m < 4; ++m)
#pragma unroll
        for (int n = 0; n < 4; ++n) {
            int r = row0 + wm * 64 + m * 16 + ((lane >> 4) << 2);
            int c = col0 + wn * 64 + n * 16 + (lane & 15);
#pragma unroll
            for (int j = 0; j < 4; ++j)
                C[(size_t)(r + j) * OUT_F + c] = acc[m][n][j];
        }
}

extern "C" void kernel_launch(void* const* d_in, const int* in_sizes, int n_in,
                              void* d_out, int out_size, void* d_ws, size_t ws_size,
                              hipStream_t stream) {
    const float* x = (const float*)d_in[0];
    const int* qw = (const int*)d_in[1];
    const int* qz = (const int*)d_in[2];
    const float* sc = (const float*)d_in[3];
    float* out = (float*)d_out;

    const size_t xq_b = (size_t)TOKENS * IN_F;       // 16 MB
    const size_t sx_b = (size_t)TOKENS * 4;          // 16 KB
    const size_t sw_b = (size_t)OUT_F * 4;           // 44 KB
    const size_t wq_b = (size_t)OUT_F * IN_F;        // 45 MB
    const size_t need = xq_b + sx_b + 2 * sw_b + wq_b;

    if (ws_size >= need) {
        signed char* xq = (signed char*)d_ws;
        float* sx = (float*)((char*)d_ws + xq_b);
        float* sw = (float*)((char*)d_ws + xq_b + sx_b);
        float* rw = (float*)((char*)d_ws + xq_b + sx_b + sw_b);
        signed char* wq = (signed char*)((char*)d_ws + xq_b + sx_b + 2 * sw_b);
        quant_x_kernel<<<TOKENS, 256, 0, stream>>>(x, xq, sx);
        sw_kernel<<<OUT_F / 256, 256, 0, stream>>>(qz, sc, sw, rw);
        quant_w8_kernel<<<(OUT_F * PACKS) / 256, 256, 0, stream>>>(qw, qz, sc, rw, wq);
        const int ngemm = (TOKENS / BM) * (OUT_F / BN);   // 688
        gemm_i8_kernel<<<ngemm, 512, 0, stream>>>(xq, wq, sw, sx, out);
    } else {
        gemm_fused_kernel<<<(TOKENS / 128) * (OUT_F / 128), 256, 0, stream>>>(x, qw, qz, sc, out);
    }
}